// Round 17
// baseline (116.883 us; speedup 1.0000x reference)
//
#include <hip/hip_runtime.h>
#include <hip/hip_bf16.h>

#define Bz 16
#define Sz 2048
#define DMz 1024
#define DHz 128

typedef __attribute__((ext_vector_type(8))) short short8;
typedef __attribute__((ext_vector_type(8))) __bf16 bf16x8;
typedef __attribute__((ext_vector_type(4))) float f32x4;

static __device__ __forceinline__ unsigned short f2bf(float f) {
  union { float f; unsigned u; } x; x.f = f;
  unsigned r = x.u + 0x7fffu + ((x.u >> 16) & 1u);
  return (unsigned short)(r >> 16);
}

static __device__ __forceinline__ f32x4 mfma16(short8 a, short8 b, f32x4 c) {
  return __builtin_amdgcn_mfma_f32_16x16x32_bf16(
      __builtin_bit_cast(bf16x8, a), __builtin_bit_cast(bf16x8, b), c, 0, 0, 0);
}

typedef const __attribute__((address_space(1))) void gvoid_t;
typedef __attribute__((address_space(3))) void lvoid_t;
static __device__ __forceinline__ void g2lds16(const void* gp, void* lp) {
  __builtin_amdgcn_global_load_lds((gvoid_t*)gp, (lvoid_t*)lp, 16, 0, 0);
}

static __device__ __forceinline__ short8 cvt8(float4 a, float4 b) {
  bf16x8 r;
  r[0] = (__bf16)a.x; r[1] = (__bf16)a.y; r[2] = (__bf16)a.z; r[3] = (__bf16)a.w;
  r[4] = (__bf16)b.x; r[5] = (__bf16)b.y; r[6] = (__bf16)b.z; r[7] = (__bf16)b.w;
  return __builtin_bit_cast(short8, r);
}

static __device__ __forceinline__ unsigned pkbf(float a, float b) {
  __bf16 x = (__bf16)a, y = (__bf16)b;
  unsigned short ux = __builtin_bit_cast(unsigned short, x);
  unsigned short uy = __builtin_bit_cast(unsigned short, y);
  return (unsigned)ux | ((unsigned)uy << 16);
}

// ---------------- prep: Wt[j][n][kd] = W_j[kd][n] as bf16 ----------------
__global__ void prep_w_kernel(const float* __restrict__ Wq,
                              const float* __restrict__ Wk,
                              const float* __restrict__ Wv,
                              unsigned short* __restrict__ Wt) {
  int idx = blockIdx.x * 256 + threadIdx.x;
  int j = idx >> 17;
  int rem = idx & 131071;
  int n = rem >> 10;
  int kd = rem & 1023;
  const float* W = (j == 0) ? Wq : (j == 1) ? Wk : Wv;
  Wt[idx] = f2bf(W[kd * DHz + n]);
}

// ---------------- proj: BK=32 / 3-blocks-per-CU GEMM ---------------------
// 256 thr / 4 waves (1M x 4N); block tile 64 x 384 (wave 64x96); BK=32,
// 32 steps, grid 512. LDS 32KB (A dbuf 2x4KB + B single 24KB) -> 3
// blocks/CU (register-limited: ~64 VGPR + 96 AGPR acc ~ 160/thread).
// Same barrier/staging pattern as round-11 best; only BK/LDS changed.
// 64B LDS rows -> (row&3)<<4 XOR swizzle (~4-way residual, acceptable).
__global__ __launch_bounds__(256, 3) void proj_kernel(
    const float* __restrict__ x, const unsigned short* __restrict__ Wt,
    const float* __restrict__ bq, const float* __restrict__ bk,
    const float* __restrict__ bv,
    unsigned short* __restrict__ qo, unsigned short* __restrict__ ko,
    unsigned short* __restrict__ vo) {
  __shared__ char Alds[2][4096];    // [64 rows][32 k] bf16, 64B rows
  __shared__ char Blds[24576];      // [384 cols][32 k] bf16, 64B rows
  const int t = threadIdx.x;
  const int w = t >> 6, l = t & 63;
  const int l15 = l & 15, lh = l >> 4;
  const int rb = blockIdx.x * 64;
  const int colbase = w * 96;

  f32x4 acc[4][6];
#pragma unroll
  for (int i = 0; i < 4; i++)
#pragma unroll
    for (int c = 0; c < 6; c++) acc[i][c] = (f32x4){0.f, 0.f, 0.f, 0.f};

  // ---- A staging (reg path): thread -> row=t>>2 (0..63), chunk=t&3 (32B)
  const int arow = t >> 2, achk = t & 3;
  const float* asrc = x + (rb + arow) * DMz + achk * 8;
  const int asw = (arow & 3) << 4;
  float4 areg[2];

  auto a_issue = [&](int step) {
    areg[0] = *(const float4*)(asrc + step * 32);
    areg[1] = *(const float4*)(asrc + step * 32 + 4);
  };
  auto a_write = [&](int buf) {
    short8 v = cvt8(areg[0], areg[1]);
    *(short8*)(&Alds[buf][(arow * 64 + achk * 16) ^ asw]) = v;
  };
  // ---- B staging: 24KB via global_load_lds, linear dest + inv-swz source
  auto b_stage = [&](int step) {
#pragma unroll
    for (int j = 0; j < 6; ++j) {
      int o = j * 4096 + t * 16;
      int col = o >> 6;
      int cb = (o & 63) ^ ((col & 3) << 4);
      g2lds16(Wt + col * DMz + step * 32 + (cb >> 1),
              &Blds[j * 4096 + w * 1024]);
    }
  };
  auto compute = [&](int cur) {
    short8 bfr[6];
#pragma unroll
    for (int ct = 0; ct < 6; ++ct) {
      int col = colbase + ct * 16 + l15;
      bfr[ct] =
          *(const short8*)(&Blds[(col * 64 + lh * 16) ^ ((col & 3) << 4)]);
    }
    short8 af[4];
#pragma unroll
    for (int rt = 0; rt < 4; ++rt) {
      int row = rt * 16 + l15;
      af[rt] =
          *(const short8*)(&Alds[cur][(row * 64 + lh * 16) ^ ((row & 3) << 4)]);
    }
    __builtin_amdgcn_s_setprio(1);
#pragma unroll
    for (int rt = 0; rt < 4; ++rt)
#pragma unroll
      for (int ct = 0; ct < 6; ++ct)
        acc[rt][ct] = mfma16(af[rt], bfr[ct], acc[rt][ct]);
    __builtin_amdgcn_s_setprio(0);
  };

  // ---- prologue: stage tile 0
  b_stage(0);
  a_issue(0);
  a_write(0);

  for (int step = 0; step < 32; ++step) {
    __syncthreads();                 // own B-DMA drained + A writes visible
    const int cur = step & 1;
    if (step < 31) a_issue(step + 1);
    compute(cur);
    if (step < 31) a_write(cur ^ 1);
    __syncthreads();                 // all waves done reading B(step)
    if (step < 31) b_stage(step + 1);
  }

  // ---- epilogue
#pragma unroll
  for (int ct = 0; ct < 6; ++ct) {
    int col = colbase + ct * 16 + l15;
    int tsel = col >> 7, n = col & 127;
    float bias = (tsel == 0) ? bq[n] : (tsel == 1) ? bk[n] : bv[n];
#pragma unroll
    for (int rt = 0; rt < 4; ++rt) {
#pragma unroll
      for (int r = 0; r < 4; ++r) {
        int row = rb + rt * 16 + lh * 4 + r;
        float v = acc[rt][ct][r] + bias;
        if (tsel == 0) {
          qo[row * DHz + n] = f2bf(v * 0.03125f);  // fold scale 1/sqrt(1024)
        } else if (tsel == 1) {
          ko[row * DHz + n] = f2bf(v);
        } else {
          int b = row >> 11, s = row & 2047;
          vo[(b * DHz + n) * Sz + s] = f2bf(v);
        }
      }
    }
  }
}

// ---------------- attn: swapped-QK flash + defer-max + XCD swizzle -------
// 1D grid 512, 256 thr / 4 waves, wave = 16 q-rows, KBLK = 64.
// XCD-aware bijective swizzle (512%8==0): swz = (bid&7)*64 + bid>>3 gives
// each XCD a contiguous 64-block range = 2 batches -> K/V (2MB) L2-resident
// per XCD. Defer-max THR=8, per-lane lsum (zero cross-lane on deferred).
__global__ __launch_bounds__(256) void attn_kernel(
    const unsigned short* __restrict__ qi, const unsigned short* __restrict__ ki,
    const unsigned short* __restrict__ vi, float* __restrict__ out) {
  __shared__ char lds[73728];  // K[2][16KB] | V[2][16KB] | P[4][2KB]
  const int t = threadIdx.x;
  const int w = t >> 6, l = t & 63;
  const int l15 = l & 15, lh = l >> 4;
  const int bid = blockIdx.x;
  const int swz = ((bid & 7) << 6) | (bid >> 3);   // bijective digit swap
  const int qblk = swz & 31;
  const int b = swz >> 5;
  const int qb0 = (31 - qblk) * 64;                // long blocks first
  const unsigned short* kg = ki + b * Sz * DHz;
  const unsigned short* vg = vi + b * DHz * Sz;
  char* pt = lds + 65536 + w * 2048;
  const int psw = (l15 & 7) << 4;

  short8 qf[4];
  const unsigned short* qp = qi + (b * Sz + qb0 + w * 16 + l15) * DHz + lh * 8;
#pragma unroll
  for (int c = 0; c < 4; ++c) qf[c] = *(const short8*)(qp + c * 32);

  f32x4 o[8];
#pragma unroll
  for (int d = 0; d < 8; ++d) o[d] = (f32x4){0.f, 0.f, 0.f, 0.f};
  float m_l = -1e30f, lsum_l = 0.f;  // m shared per q-row; lsum PER-LANE
  const int nit = qb0 / 64 + 1;

  auto stage = [&](int buf, int kb) {
    char* kt = lds + buf * 16384;
    char* vt = lds + 32768 + buf * 16384;
#pragma unroll
    for (int j = 0; j < 4; ++j) {  // K tile [64][128]: 256B rows
      int o_ = (w * 4 + j) * 1024 + l * 16;
      int row = o_ >> 8;
      int cb = (o_ & 255) ^ ((row & 7) << 4);
      g2lds16(kg + (kb + row) * DHz + (cb >> 1), kt + (w * 4 + j) * 1024);
    }
#pragma unroll
    for (int j = 0; j < 4; ++j) {  // Vt tile [128][64]: 128B rows
      int o_ = (w * 4 + j) * 1024 + l * 16;
      int row = o_ >> 7;
      int cb = (o_ & 127) ^ ((row & 7) << 4);
      g2lds16(vg + row * Sz + kb + (cb >> 1), vt + (w * 4 + j) * 1024);
    }
  };

  stage(0, 0);
  for (int it = 0; it < nit; ++it) {
    const int kb = it * 64;
    const int cur = it & 1;
    __syncthreads();
    if (it + 1 < nit) stage(cur ^ 1, kb + 64);
    const char* kt = lds + cur * 16384;
    const char* vt = lds + 32768 + cur * 16384;

    // ---- QK^T (swapped): sc[toff][r] = S[k = kb+toff*16+lh*4+r][q = l15]
    f32x4 sc[4];
    __builtin_amdgcn_s_setprio(1);
#pragma unroll
    for (int toff = 0; toff < 4; ++toff) {
      int key = toff * 16 + l15;
      int sw = (key & 7) << 4;
      f32x4 s4 = (f32x4){0.f, 0.f, 0.f, 0.f};
#pragma unroll
      for (int c = 0; c < 4; ++c) {
        short8 kf = *(const short8*)(kt + key * 256 + ((c * 64 + lh * 16) ^ sw));
        s4 = mfma16(kf, qf[c], s4);
      }
      sc[toff] = s4;
    }
    __builtin_amdgcn_s_setprio(0);

    // ---- mask (diagonal tiles only; wave-uniform branch)
    if (kb + 63 > qb0 + w * 16) {
      const int q = qb0 + w * 16 + l15;
#pragma unroll
      for (int toff = 0; toff < 4; ++toff)
#pragma unroll
        for (int r = 0; r < 4; ++r)
          if (kb + toff * 16 + lh * 4 + r > q) sc[toff][r] = -1e30f;
    }

    // ---- softmax with defer-max (THR=8)
    float mx01 = fmaxf(fmaxf(sc[0][0], sc[0][1]), fmaxf(sc[0][2], sc[0][3]));
    float mx23 = fmaxf(fmaxf(sc[1][0], sc[1][1]), fmaxf(sc[1][2], sc[1][3]));
    float mx45 = fmaxf(fmaxf(sc[2][0], sc[2][1]), fmaxf(sc[2][2], sc[2][3]));
    float mx67 = fmaxf(fmaxf(sc[3][0], sc[3][1]), fmaxf(sc[3][2], sc[3][3]));
    float pmx = fmaxf(fmaxf(mx01, mx23), fmaxf(mx45, mx67));
    float p[4][4];
    if (__all(pmx <= m_l + 8.f)) {
      // deferred: keep old max, no rescale, no cross-lane ops
      float ps = 0.f;
#pragma unroll
      for (int toff = 0; toff < 4; ++toff) {
        float s0 = __expf(sc[toff][0] - m_l), s1 = __expf(sc[toff][1] - m_l);
        float s2 = __expf(sc[toff][2] - m_l), s3 = __expf(sc[toff][3] - m_l);
        p[toff][0] = s0; p[toff][1] = s1; p[toff][2] = s2; p[toff][3] = s3;
        ps += (s0 + s1) + (s2 + s3);
      }
      lsum_l += ps;
    } else {
      float pm = pmx;
      pm = fmaxf(pm, __shfl_xor(pm, 16));
      pm = fmaxf(pm, __shfl_xor(pm, 32));
      const float mn = fmaxf(m_l, pm);
      const float fsc = __expf(m_l - mn);
      float ps = 0.f;
#pragma unroll
      for (int toff = 0; toff < 4; ++toff) {
        float s0 = __expf(sc[toff][0] - mn), s1 = __expf(sc[toff][1] - mn);
        float s2 = __expf(sc[toff][2] - mn), s3 = __expf(sc[toff][3] - mn);
        p[toff][0] = s0; p[toff][1] = s1; p[toff][2] = s2; p[toff][3] = s3;
        ps += (s0 + s1) + (s2 + s3);
      }
      lsum_l = lsum_l * fsc + ps;
      m_l = mn;
      float fr[4];
#pragma unroll
      for (int r = 0; r < 4; ++r) fr[r] = __shfl(fsc, lh * 4 + r);
#pragma unroll
      for (int dt = 0; dt < 8; ++dt) {
        o[dt][0] *= fr[0]; o[dt][1] *= fr[1];
        o[dt][2] *= fr[2]; o[dt][3] *= fr[3];
      }
    }

    // ---- P -> per-wave LDS tile [16 rows q][64 k] bf16, XOR-swizzled
#pragma unroll
    for (int toff = 0; toff < 4; ++toff) {
      unsigned w0 = pkbf(p[toff][0], p[toff][1]);
      unsigned w1 = pkbf(p[toff][2], p[toff][3]);
      int byte = (l15 * 128 + toff * 32 + lh * 8) ^ psw;
      *(uint2*)(pt + byte) = (uint2){w0, w1};
    }

    // ---- PV: O[q][d] += P[q][k] * Vt[d][k]
    __builtin_amdgcn_s_setprio(1);
#pragma unroll
    for (int ks = 0; ks < 2; ++ks) {
      short8 pf = *(const short8*)(pt + ((l15 * 128 + ks * 64 + lh * 16) ^ psw));
#pragma unroll
      for (int dt = 0; dt < 8; ++dt) {
        int dd = dt * 16 + l15;
        short8 vf = *(const short8*)(vt + dd * 128 +
                                     ((ks * 64 + lh * 16) ^ ((dd & 7) << 4)));
        o[dt] = mfma16(pf, vf, o[dt]);
      }
    }
    __builtin_amdgcn_s_setprio(0);
  }

  // ---- combine per-lane partial lsum across the 4 lanes of each q-row
  lsum_l += __shfl_xor(lsum_l, 16);
  lsum_l += __shfl_xor(lsum_l, 32);
#pragma unroll
  for (int r = 0; r < 4; ++r) {
    const float inv = 1.f / __shfl(lsum_l, lh * 4 + r);
    float* op = out + (b * Sz + qb0 + w * 16 + lh * 4 + r) * DHz + l15;
#pragma unroll
    for (int dt = 0; dt < 8; ++dt) op[dt * 16] = o[dt][r] * inv;
  }
}

extern "C" void kernel_launch(void* const* d_in, const int* in_sizes, int n_in,
                              void* d_out, int out_size, void* d_ws,
                              size_t ws_size, hipStream_t stream) {
  (void)in_sizes; (void)n_in; (void)out_size; (void)ws_size;
  const float* x  = (const float*)d_in[0];
  const float* Wq = (const float*)d_in[1];
  const float* bq = (const float*)d_in[2];
  const float* Wk = (const float*)d_in[3];
  const float* bk = (const float*)d_in[4];
  const float* Wv = (const float*)d_in[5];
  const float* bv = (const float*)d_in[6];

  unsigned short* Wt = (unsigned short*)d_ws;          // 3*128*1024
  unsigned short* qo = Wt + 3 * DHz * DMz;             // B*S*128
  unsigned short* ko = qo + Bz * Sz * DHz;
  unsigned short* vo = ko + Bz * Sz * DHz;             // transposed [B][128][S]

  prep_w_kernel<<<(3 * DHz * DMz) / 256, 256, 0, stream>>>(Wq, Wk, Wv, Wt);
  proj_kernel<<<(Bz * Sz) / 64, 256, 0, stream>>>(x, Wt, bq, bk, bv, qo, ko, vo);
  attn_kernel<<<Bz * (Sz / 64), 256, 0, stream>>>(qo, ko, vo, (float*)d_out);
}

// Round 18
// 108.562 us; speedup vs baseline: 1.0766x; 1.0766x over previous
//
#include <hip/hip_runtime.h>
#include <hip/hip_bf16.h>

#define Bz 16
#define Sz 2048
#define DMz 1024
#define DHz 128

typedef __attribute__((ext_vector_type(8))) short short8;
typedef __attribute__((ext_vector_type(8))) __bf16 bf16x8;
typedef __attribute__((ext_vector_type(4))) float f32x4;

static __device__ __forceinline__ unsigned short f2bf(float f) {
  union { float f; unsigned u; } x; x.f = f;
  unsigned r = x.u + 0x7fffu + ((x.u >> 16) & 1u);
  return (unsigned short)(r >> 16);
}

static __device__ __forceinline__ f32x4 mfma16(short8 a, short8 b, f32x4 c) {
  return __builtin_amdgcn_mfma_f32_16x16x32_bf16(
      __builtin_bit_cast(bf16x8, a), __builtin_bit_cast(bf16x8, b), c, 0, 0, 0);
}

typedef const __attribute__((address_space(1))) void gvoid_t;
typedef __attribute__((address_space(3))) void lvoid_t;
static __device__ __forceinline__ void g2lds16(const void* gp, void* lp) {
  __builtin_amdgcn_global_load_lds((gvoid_t*)gp, (lvoid_t*)lp, 16, 0, 0);
}

static __device__ __forceinline__ short8 cvt8(float4 a, float4 b) {
  bf16x8 r;
  r[0] = (__bf16)a.x; r[1] = (__bf16)a.y; r[2] = (__bf16)a.z; r[3] = (__bf16)a.w;
  r[4] = (__bf16)b.x; r[5] = (__bf16)b.y; r[6] = (__bf16)b.z; r[7] = (__bf16)b.w;
  return __builtin_bit_cast(short8, r);
}

static __device__ __forceinline__ unsigned pkbf(float a, float b) {
  __bf16 x = (__bf16)a, y = (__bf16)b;
  unsigned short ux = __builtin_bit_cast(unsigned short, x);
  unsigned short uy = __builtin_bit_cast(unsigned short, y);
  return (unsigned)ux | ((unsigned)uy << 16);
}

// ---------------- prep: Wt[j][n][kd] = W_j[kd][n] as bf16 ----------------
__global__ void prep_w_kernel(const float* __restrict__ Wq,
                              const float* __restrict__ Wk,
                              const float* __restrict__ Wv,
                              unsigned short* __restrict__ Wt) {
  int idx = blockIdx.x * 256 + threadIdx.x;
  int j = idx >> 17;
  int rem = idx & 131071;
  int n = rem >> 10;
  int kd = rem & 1023;
  const float* W = (j == 0) ? Wq : (j == 1) ? Wk : Wv;
  Wt[idx] = f2bf(W[kd * DHz + n]);
}

// ---------------- proj: BM=64 / 2-blocks-per-CU GEMM (round-11 best) -----
// 256 thr / 4 waves (1M x 4N); block tile 64 x 384 (wave 64x96, acc 4x6);
// BK=64, 16 steps, grid 512 -> 2 blocks/CU (cross-block overlap, m114).
// x read ONCE. LDS 64KB: A dbuf 2x8KB + B single 48KB (stage-after-2nd-
// barrier; other block's compute hides the DMA drain).
__global__ __launch_bounds__(256, 2) void proj_kernel(
    const float* __restrict__ x, const unsigned short* __restrict__ Wt,
    const float* __restrict__ bq, const float* __restrict__ bk,
    const float* __restrict__ bv,
    unsigned short* __restrict__ qo, unsigned short* __restrict__ ko,
    unsigned short* __restrict__ vo) {
  __shared__ char Alds[2][8192];    // [64 rows][64 k] bf16, 128B rows
  __shared__ char Blds[49152];      // [384 cols][64 k] bf16, 128B rows
  const int t = threadIdx.x;
  const int w = t >> 6, l = t & 63;
  const int l15 = l & 15, lh = l >> 4;
  const int rb = blockIdx.x * 64;
  const int colbase = w * 96;

  f32x4 acc[4][6];
#pragma unroll
  for (int i = 0; i < 4; i++)
#pragma unroll
    for (int c = 0; c < 6; c++) acc[i][c] = (f32x4){0.f, 0.f, 0.f, 0.f};

  // ---- A staging (reg path): thread -> row=t>>2 (0..63), chunk=t&3 (64B)
  const int arow = t >> 2, achk = t & 3;
  const float* asrc = x + (rb + arow) * DMz + achk * 16;
  const int asw = (arow & 7) << 4;
  float4 areg[4];

  auto a_issue = [&](int step) {
#pragma unroll
    for (int j = 0; j < 4; ++j)
      areg[j] = *(const float4*)(asrc + step * 64 + j * 4);
  };
  auto a_write = [&](int buf) {
    short8 lo = cvt8(areg[0], areg[1]);
    short8 hi = cvt8(areg[2], areg[3]);
    *(short8*)(&Alds[buf][(arow * 128 + achk * 32) ^ asw]) = lo;
    *(short8*)(&Alds[buf][(arow * 128 + achk * 32 + 16) ^ asw]) = hi;
  };
  // ---- B staging: 48KB via global_load_lds, linear dest + inv-swz source
  auto b_stage = [&](int step) {
#pragma unroll
    for (int j = 0; j < 12; ++j) {
      int o = j * 4096 + t * 16;
      int col = o >> 7;
      int cb = (o & 127) ^ ((col & 7) << 4);
      g2lds16(Wt + col * DMz + step * 64 + (cb >> 1),
              &Blds[j * 4096 + w * 1024]);
    }
  };
  auto compute = [&](int cur) {
#pragma unroll
    for (int sub = 0; sub < 2; ++sub) {
      short8 bfr[6];
#pragma unroll
      for (int ct = 0; ct < 6; ++ct) {
        int col = colbase + ct * 16 + l15;
        bfr[ct] = *(const short8*)(&Blds[(col * 128 + sub * 64 + lh * 16) ^
                                         ((col & 7) << 4)]);
      }
      short8 af[4];
#pragma unroll
      for (int rt = 0; rt < 4; ++rt) {
        int row = rt * 16 + l15;
        af[rt] = *(const short8*)(&Alds[cur][(row * 128 + sub * 64 + lh * 16) ^
                                             ((row & 7) << 4)]);
      }
      __builtin_amdgcn_s_setprio(1);
#pragma unroll
      for (int rt = 0; rt < 4; ++rt)
#pragma unroll
        for (int ct = 0; ct < 6; ++ct)
          acc[rt][ct] = mfma16(af[rt], bfr[ct], acc[rt][ct]);
      __builtin_amdgcn_s_setprio(0);
    }
  };

  // ---- prologue: stage tile 0
  b_stage(0);
  a_issue(0);
  a_write(0);

  for (int step = 0; step < 16; ++step) {
    __syncthreads();                 // own B-DMA drained + A writes visible
    const int cur = step & 1;
    if (step < 15) a_issue(step + 1);
    compute(cur);
    if (step < 15) a_write(cur ^ 1);
    __syncthreads();                 // all waves done reading B(step)
    if (step < 15) b_stage(step + 1);
  }

  // ---- epilogue
#pragma unroll
  for (int ct = 0; ct < 6; ++ct) {
    int col = colbase + ct * 16 + l15;
    int tsel = col >> 7, n = col & 127;
    float bias = (tsel == 0) ? bq[n] : (tsel == 1) ? bk[n] : bv[n];
#pragma unroll
    for (int rt = 0; rt < 4; ++rt) {
#pragma unroll
      for (int r = 0; r < 4; ++r) {
        int row = rb + rt * 16 + lh * 4 + r;
        float v = acc[rt][ct][r] + bias;
        if (tsel == 0) {
          qo[row * DHz + n] = f2bf(v * 0.03125f);  // fold scale 1/sqrt(1024)
        } else if (tsel == 1) {
          ko[row * DHz + n] = f2bf(v);
        } else {
          int b = row >> 11, s = row & 2047;
          vo[(b * DHz + n) * Sz + s] = f2bf(v);
        }
      }
    }
  }
}

// ---------------- attn: swapped-QK flash + defer-max + XCD swizzle -------
// 1D grid 512, 256 thr / 4 waves, wave = 16 q-rows, KBLK = 64.
// XCD-aware bijective swizzle (512%8==0): swz = (bid&7)*64 + bid>>3 gives
// each XCD a contiguous 64-block range = 2 batches -> K/V (2MB) L2-resident
// per XCD. Defer-max THR=8, per-lane lsum (zero cross-lane on deferred).
__global__ __launch_bounds__(256) void attn_kernel(
    const unsigned short* __restrict__ qi, const unsigned short* __restrict__ ki,
    const unsigned short* __restrict__ vi, float* __restrict__ out) {
  __shared__ char lds[73728];  // K[2][16KB] | V[2][16KB] | P[4][2KB]
  const int t = threadIdx.x;
  const int w = t >> 6, l = t & 63;
  const int l15 = l & 15, lh = l >> 4;
  const int bid = blockIdx.x;
  const int swz = ((bid & 7) << 6) | (bid >> 3);   // bijective digit swap
  const int qblk = swz & 31;
  const int b = swz >> 5;
  const int qb0 = (31 - qblk) * 64;                // long blocks first
  const unsigned short* kg = ki + b * Sz * DHz;
  const unsigned short* vg = vi + b * DHz * Sz;
  char* pt = lds + 65536 + w * 2048;
  const int psw = (l15 & 7) << 4;

  short8 qf[4];
  const unsigned short* qp = qi + (b * Sz + qb0 + w * 16 + l15) * DHz + lh * 8;
#pragma unroll
  for (int c = 0; c < 4; ++c) qf[c] = *(const short8*)(qp + c * 32);

  f32x4 o[8];
#pragma unroll
  for (int d = 0; d < 8; ++d) o[d] = (f32x4){0.f, 0.f, 0.f, 0.f};
  float m_l = -1e30f, lsum_l = 0.f;  // m shared per q-row; lsum PER-LANE
  const int nit = qb0 / 64 + 1;

  auto stage = [&](int buf, int kb) {
    char* kt = lds + buf * 16384;
    char* vt = lds + 32768 + buf * 16384;
#pragma unroll
    for (int j = 0; j < 4; ++j) {  // K tile [64][128]: 256B rows
      int o_ = (w * 4 + j) * 1024 + l * 16;
      int row = o_ >> 8;
      int cb = (o_ & 255) ^ ((row & 7) << 4);
      g2lds16(kg + (kb + row) * DHz + (cb >> 1), kt + (w * 4 + j) * 1024);
    }
#pragma unroll
    for (int j = 0; j < 4; ++j) {  // Vt tile [128][64]: 128B rows
      int o_ = (w * 4 + j) * 1024 + l * 16;
      int row = o_ >> 7;
      int cb = (o_ & 127) ^ ((row & 7) << 4);
      g2lds16(vg + row * Sz + kb + (cb >> 1), vt + (w * 4 + j) * 1024);
    }
  };

  stage(0, 0);
  for (int it = 0; it < nit; ++it) {
    const int kb = it * 64;
    const int cur = it & 1;
    __syncthreads();
    if (it + 1 < nit) stage(cur ^ 1, kb + 64);
    const char* kt = lds + cur * 16384;
    const char* vt = lds + 32768 + cur * 16384;

    // ---- QK^T (swapped): sc[toff][r] = S[k = kb+toff*16+lh*4+r][q = l15]
    f32x4 sc[4];
    __builtin_amdgcn_s_setprio(1);
#pragma unroll
    for (int toff = 0; toff < 4; ++toff) {
      int key = toff * 16 + l15;
      int sw = (key & 7) << 4;
      f32x4 s4 = (f32x4){0.f, 0.f, 0.f, 0.f};
#pragma unroll
      for (int c = 0; c < 4; ++c) {
        short8 kf = *(const short8*)(kt + key * 256 + ((c * 64 + lh * 16) ^ sw));
        s4 = mfma16(kf, qf[c], s4);
      }
      sc[toff] = s4;
    }
    __builtin_amdgcn_s_setprio(0);

    // ---- mask (diagonal tiles only; wave-uniform branch)
    if (kb + 63 > qb0 + w * 16) {
      const int q = qb0 + w * 16 + l15;
#pragma unroll
      for (int toff = 0; toff < 4; ++toff)
#pragma unroll
        for (int r = 0; r < 4; ++r)
          if (kb + toff * 16 + lh * 4 + r > q) sc[toff][r] = -1e30f;
    }

    // ---- softmax with defer-max (THR=8)
    float mx01 = fmaxf(fmaxf(sc[0][0], sc[0][1]), fmaxf(sc[0][2], sc[0][3]));
    float mx23 = fmaxf(fmaxf(sc[1][0], sc[1][1]), fmaxf(sc[1][2], sc[1][3]));
    float mx45 = fmaxf(fmaxf(sc[2][0], sc[2][1]), fmaxf(sc[2][2], sc[2][3]));
    float mx67 = fmaxf(fmaxf(sc[3][0], sc[3][1]), fmaxf(sc[3][2], sc[3][3]));
    float pmx = fmaxf(fmaxf(mx01, mx23), fmaxf(mx45, mx67));
    float p[4][4];
    if (__all(pmx <= m_l + 8.f)) {
      // deferred: keep old max, no rescale, no cross-lane ops
      float ps = 0.f;
#pragma unroll
      for (int toff = 0; toff < 4; ++toff) {
        float s0 = __expf(sc[toff][0] - m_l), s1 = __expf(sc[toff][1] - m_l);
        float s2 = __expf(sc[toff][2] - m_l), s3 = __expf(sc[toff][3] - m_l);
        p[toff][0] = s0; p[toff][1] = s1; p[toff][2] = s2; p[toff][3] = s3;
        ps += (s0 + s1) + (s2 + s3);
      }
      lsum_l += ps;
    } else {
      float pm = pmx;
      pm = fmaxf(pm, __shfl_xor(pm, 16));
      pm = fmaxf(pm, __shfl_xor(pm, 32));
      const float mn = fmaxf(m_l, pm);
      const float fsc = __expf(m_l - mn);
      float ps = 0.f;
#pragma unroll
      for (int toff = 0; toff < 4; ++toff) {
        float s0 = __expf(sc[toff][0] - mn), s1 = __expf(sc[toff][1] - mn);
        float s2 = __expf(sc[toff][2] - mn), s3 = __expf(sc[toff][3] - mn);
        p[toff][0] = s0; p[toff][1] = s1; p[toff][2] = s2; p[toff][3] = s3;
        ps += (s0 + s1) + (s2 + s3);
      }
      lsum_l = lsum_l * fsc + ps;
      m_l = mn;
      float fr[4];
#pragma unroll
      for (int r = 0; r < 4; ++r) fr[r] = __shfl(fsc, lh * 4 + r);
#pragma unroll
      for (int dt = 0; dt < 8; ++dt) {
        o[dt][0] *= fr[0]; o[dt][1] *= fr[1];
        o[dt][2] *= fr[2]; o[dt][3] *= fr[3];
      }
    }

    // ---- P -> per-wave LDS tile [16 rows q][64 k] bf16, XOR-swizzled
#pragma unroll
    for (int toff = 0; toff < 4; ++toff) {
      unsigned w0 = pkbf(p[toff][0], p[toff][1]);
      unsigned w1 = pkbf(p[toff][2], p[toff][3]);
      int byte = (l15 * 128 + toff * 32 + lh * 8) ^ psw;
      *(uint2*)(pt + byte) = (uint2){w0, w1};
    }

    // ---- PV: O[q][d] += P[q][k] * Vt[d][k]
    __builtin_amdgcn_s_setprio(1);
#pragma unroll
    for (int ks = 0; ks < 2; ++ks) {
      short8 pf = *(const short8*)(pt + ((l15 * 128 + ks * 64 + lh * 16) ^ psw));
#pragma unroll
      for (int dt = 0; dt < 8; ++dt) {
        int dd = dt * 16 + l15;
        short8 vf = *(const short8*)(vt + dd * 128 +
                                     ((ks * 64 + lh * 16) ^ ((dd & 7) << 4)));
        o[dt] = mfma16(pf, vf, o[dt]);
      }
    }
    __builtin_amdgcn_s_setprio(0);
  }

  // ---- combine per-lane partial lsum across the 4 lanes of each q-row
  lsum_l += __shfl_xor(lsum_l, 16);
  lsum_l += __shfl_xor(lsum_l, 32);
#pragma unroll
  for (int r = 0; r < 4; ++r) {
    const float inv = 1.f / __shfl(lsum_l, lh * 4 + r);
    float* op = out + (b * Sz + qb0 + w * 16 + lh * 4 + r) * DHz + l15;
#pragma unroll
    for (int dt = 0; dt < 8; ++dt) op[dt * 16] = o[dt][r] * inv;
  }
}

extern "C" void kernel_launch(void* const* d_in, const int* in_sizes, int n_in,
                              void* d_out, int out_size, void* d_ws,
                              size_t ws_size, hipStream_t stream) {
  (void)in_sizes; (void)n_in; (void)out_size; (void)ws_size;
  const float* x  = (const float*)d_in[0];
  const float* Wq = (const float*)d_in[1];
  const float* bq = (const float*)d_in[2];
  const float* Wk = (const float*)d_in[3];
  const float* bk = (const float*)d_in[4];
  const float* Wv = (const float*)d_in[5];
  const float* bv = (const float*)d_in[6];

  unsigned short* Wt = (unsigned short*)d_ws;          // 3*128*1024
  unsigned short* qo = Wt + 3 * DHz * DMz;             // B*S*128
  unsigned short* ko = qo + Bz * Sz * DHz;
  unsigned short* vo = ko + Bz * Sz * DHz;             // transposed [B][128][S]

  prep_w_kernel<<<(3 * DHz * DMz) / 256, 256, 0, stream>>>(Wq, Wk, Wv, Wt);
  proj_kernel<<<(Bz * Sz) / 64, 256, 0, stream>>>(x, Wt, bq, bk, bv, qo, ko, vo);
  attn_kernel<<<Bz * (Sz / 64), 256, 0, stream>>>(qo, ko, vo, (float*)d_out);
}